// Round 1
// baseline (5144.963 us; speedup 1.0000x reference)
//
#include <hip/hip_runtime.h>
#include <hip/hip_bf16.h>
#include <math.h>

#define CIN   512
#define COUT  512
#define NB    16
#define WD    512
#define HIN   32
#define HUP   66      // upsampled spatial size
#define XS_STRIDE 68  // padded row stride for xs (bf16 elements)
#define RES   64
#define LRELU 0.2f
#define ACT_GAIN 1.4142135623730951f
#define COT   8       // cout per conv block

// ---------------- styles = w @ A^T / sqrt(512) + bias ----------------
__global__ void styles_kernel(const float* __restrict__ w,
                              const float* __restrict__ aw,
                              const float* __restrict__ ab,
                              float* __restrict__ styles) {
    int b  = blockIdx.x;     // 16 blocks
    int ci = threadIdx.x;    // 512 threads
    const float* wrow = w + b * WD;
    const float* arow = aw + (size_t)ci * WD;
    float acc = 0.f;
    for (int k = 0; k < WD; ++k) acc += wrow[k] * arow[k];
    styles[b * CIN + ci] = acc * 0.04419417382415922f + ab[ci];
}

// ---- per-(co,ci) sum of squared taps; pre-flipped weight pack wpk[ci][tap][co] ----
__global__ void prep_weights(const float* __restrict__ weight,
                             float* __restrict__ wsq,
                             float* __restrict__ wpk) {
    int idx = blockIdx.x * 256 + threadIdx.x;   // 262144 threads
    int co = idx & (COUT - 1);
    int ci = idx >> 9;
    const float* wp = weight + ((size_t)co * CIN + ci) * 9;
    float s = 0.f;
#pragma unroll
    for (int t = 0; t < 9; ++t) {
        float v = wp[t];
        s += v * v;
        // flipped tap: new_t = 8 - t  (kh,kw -> 2-kh,2-kw)
        wpk[((size_t)ci * 9 + (8 - t)) * COUT + co] = v;
    }
    wsq[(size_t)co * CIN + ci] = s;
}

// ---------------- dcoef[b,co] = rsqrt( sum_ci wsq[co,ci]*styles^2 + 1e-8 ) ----------------
__global__ void dcoef_kernel(const float* __restrict__ styles,
                             const float* __restrict__ wsq,
                             float* __restrict__ dcoef) {
    int idx = blockIdx.x * 256 + threadIdx.x;   // 8192 threads
    int b  = idx >> 9;
    int co = idx & (COUT - 1);
    const float* srow = styles + b * CIN;
    const float* qrow = wsq + (size_t)co * CIN;
    float acc = 1e-8f;
    for (int ci = 0; ci < CIN; ++ci) {
        float s = srow[ci];
        acc += qrow[ci] * s * s;
    }
    dcoef[idx] = rsqrtf(acc);
}

// ---------------- upsample x2 (upfirdn [1,3,3,1]/8) * styles -> bf16 xs ----------------
__global__ void upmod_kernel(const float* __restrict__ x,
                             const float* __restrict__ styles,
                             __hip_bfloat16* __restrict__ xs) {
    int chan = blockIdx.y;                       // b*512+ci
    int px = blockIdx.x * 256 + threadIdx.x;
    if (px >= HUP * HUP) return;
    int oh = px / HUP;
    int ow = px - oh * HUP;
    float s = styles[chan] * 4.0f;               // fold k = 4*f2

    int m0, m1, n0, n1;
    float a0, a1, b0, b1;
    if (oh & 1) { m0 = (oh - 3) >> 1; a0 = 0.125f; m1 = (oh - 1) >> 1; a1 = 0.375f; }
    else        { m0 = (oh >> 1) - 1; a0 = 0.375f; m1 = (oh >> 1);     a1 = 0.125f; }
    if (ow & 1) { n0 = (ow - 3) >> 1; b0 = 0.125f; n1 = (ow - 1) >> 1; b1 = 0.375f; }
    else        { n0 = (ow >> 1) - 1; b0 = 0.375f; n1 = (ow >> 1);     b1 = 0.125f; }

    const float* xp = x + (size_t)chan * HIN * HIN;
    bool c0 = (n0 >= 0) & (n0 < HIN);
    bool c1 = (n1 >= 0) & (n1 < HIN);
    float r0 = 0.f, r1 = 0.f;
    if (m0 >= 0 && m0 < HIN) {
        const float* r = xp + m0 * HIN;
        r0 = (c0 ? r[n0] : 0.f) * b0 + (c1 ? r[n1] : 0.f) * b1;
    }
    if (m1 >= 0 && m1 < HIN) {
        const float* r = xp + m1 * HIN;
        r1 = (c0 ? r[n0] : 0.f) * b0 + (c1 ? r[n1] : 0.f) * b1;
    }
    float val = (a0 * r0 + a1 * r1) * s;
    xs[(size_t)chan * HUP * XS_STRIDE + (size_t)oh * XS_STRIDE + ow] = __float2bfloat16(val);
}

// ---------------- main conv: per block = (b, 8 cout, 32x32 px tile) ----------------
__global__ __launch_bounds__(256) void conv_kernel(
        const __hip_bfloat16* __restrict__ xs,
        const float* __restrict__ wpk,
        const float* __restrict__ dcoef,
        const float* __restrict__ bias,
        const float* __restrict__ noise,
        const float* __restrict__ nstr,
        float* __restrict__ out) {
    __shared__ float xt[34 * 36];
    __shared__ float wl[9 * 8];

    int sp  = blockIdx.x;          // 0..3 spatial tile
    int cot = blockIdx.y;          // 0..63
    int b   = blockIdx.z;          // 0..15
    int y0 = (sp >> 1) * 32, x0 = (sp & 1) * 32;
    int co0 = cot * COT;
    int tid = threadIdx.x;
    int tx = tid & 15, ty = tid >> 4;
    int py0 = ty * 2, px0 = tx * 2;

    float acc[COT][2][2];
#pragma unroll
    for (int j = 0; j < COT; ++j)
#pragma unroll
        for (int p = 0; p < 2; ++p)
#pragma unroll
            for (int q = 0; q < 2; ++q) acc[j][p][q] = 0.f;

    for (int ci = 0; ci < CIN; ++ci) {
        // stage 34x34 bf16 tile -> fp32 LDS
        const __hip_bfloat16* xp =
            xs + ((size_t)(b * CIN + ci) * HUP + y0) * XS_STRIDE + x0;
        for (int e = tid; e < 34 * 34; e += 256) {
            int r = e / 34;
            int c = e - r * 34;
            xt[r * 36 + c] = __bfloat162float(xp[r * XS_STRIDE + c]);
        }
        // stage 8co x 9tap weights (fp32, pre-flipped), layout wl[t*8+j]
        if (tid < 72) {
            int t = tid >> 3, j = tid & 7;
            wl[t * 8 + j] = wpk[((size_t)ci * 9 + t) * COUT + co0 + j];
        }
        __syncthreads();

        float p[4][4];
#pragma unroll
        for (int r = 0; r < 4; ++r) {
            const float2* row = (const float2*)&xt[(py0 + r) * 36 + px0];
            float2 u = row[0], v = row[1];
            p[r][0] = u.x; p[r][1] = u.y; p[r][2] = v.x; p[r][3] = v.y;
        }
#pragma unroll
        for (int kh = 0; kh < 3; ++kh)
#pragma unroll
            for (int kw = 0; kw < 3; ++kw) {
                int t = kh * 3 + kw;
                const float4* wv = (const float4*)&wl[t * 8];
                float4 wa = wv[0], wb = wv[1];
                float wreg[8] = {wa.x, wa.y, wa.z, wa.w, wb.x, wb.y, wb.z, wb.w};
#pragma unroll
                for (int j = 0; j < 8; ++j)
#pragma unroll
                    for (int pp = 0; pp < 2; ++pp)
#pragma unroll
                        for (int q = 0; q < 2; ++q)
                            acc[j][pp][q] += wreg[j] * p[pp + kh][q + kw];
            }
        __syncthreads();
    }

    // epilogue: *dcoef + noise*strength + bias -> lrelu*gain
    float ns = nstr[0];
#pragma unroll
    for (int j = 0; j < COT; ++j) {
        int co = co0 + j;
        float dc = dcoef[b * COUT + co];
        float bs = bias[co];
#pragma unroll
        for (int pp = 0; pp < 2; ++pp) {
            int Y = y0 + py0 + pp;
            int X = x0 + px0;
            float v0 = acc[j][pp][0] * dc + noise[Y * RES + X] * ns + bs;
            float v1 = acc[j][pp][1] * dc + noise[Y * RES + X + 1] * ns + bs;
            float2 o;
            o.x = (v0 > 0.f ? v0 : LRELU * v0) * ACT_GAIN;
            o.y = (v1 > 0.f ? v1 : LRELU * v1) * ACT_GAIN;
            *(float2*)&out[(((size_t)b * COUT + co) * RES + Y) * RES + X] = o;
        }
    }
}

extern "C" void kernel_launch(void* const* d_in, const int* in_sizes, int n_in,
                              void* d_out, int out_size, void* d_ws, size_t ws_size,
                              hipStream_t stream) {
    (void)in_sizes; (void)n_in; (void)out_size; (void)ws_size;
    const float* x     = (const float*)d_in[0];
    const float* w     = (const float*)d_in[1];
    const float* aw    = (const float*)d_in[2];
    const float* ab    = (const float*)d_in[3];
    const float* wt    = (const float*)d_in[4];
    const float* bias  = (const float*)d_in[5];
    const float* noise = (const float*)d_in[6];
    const float* nstr  = (const float*)d_in[7];
    float* out = (float*)d_out;

    char* ws = (char*)d_ws;
    float* styles = (float*)ws;                                    // 32 KB
    float* dcoef  = (float*)(ws + 32768);                          // 32 KB
    float* wsq    = (float*)(ws + 65536);                          // 1 MB
    float* wpk    = (float*)(ws + 65536 + 1048576);                // 9.4 MB
    __hip_bfloat16* xsb =
        (__hip_bfloat16*)(ws + 65536 + 1048576 + 9437184);         // 73.5 MB

    styles_kernel<<<dim3(NB), dim3(512), 0, stream>>>(w, aw, ab, styles);
    prep_weights<<<dim3(1024), dim3(256), 0, stream>>>(wt, wsq, wpk);
    dcoef_kernel<<<dim3(32), dim3(256), 0, stream>>>(styles, wsq, dcoef);
    upmod_kernel<<<dim3(18, NB * CIN), dim3(256), 0, stream>>>(x, styles, xsb);
    conv_kernel<<<dim3(4, COUT / COT, NB), dim3(256), 0, stream>>>(
        xsb, wpk, dcoef, bias, noise, nstr, out);
}

// Round 2
// 547.898 us; speedup vs baseline: 9.3904x; 9.3904x over previous
//
#include <hip/hip_runtime.h>
#include <hip/hip_bf16.h>
#include <math.h>

#define CIN   512
#define COUT  512
#define NB    16
#define WD    512
#define HIN   32
#define HUP   66
#define RES   64
#define LRELU 0.2f
#define ACT_GAIN 1.4142135623730951f

typedef __attribute__((ext_vector_type(8))) short short8;
typedef __attribute__((ext_vector_type(4))) float float4v;

// ---------------- styles = w @ A^T / sqrt(512) + bias ----------------
__global__ void styles2_kernel(const float* __restrict__ w,
                               const float* __restrict__ aw,
                               const float* __restrict__ ab,
                               float* __restrict__ styles) {
    int b = blockIdx.x;          // 16
    int cig = blockIdx.y;        // 8
    int lane = threadIdx.x & 63, wv = threadIdx.x >> 6;
    __shared__ float wsh[WD];
    for (int e = threadIdx.x; e < WD; e += 256) wsh[e] = w[b * WD + e];
    __syncthreads();
    for (int r = 0; r < 16; ++r) {
        int ci = cig * 64 + wv * 16 + r;
        const float* arow = aw + (size_t)ci * WD;
        float acc = 0.f;
        for (int k = lane; k < WD; k += 64) acc += arow[k] * wsh[k];
        for (int off = 32; off; off >>= 1) acc += __shfl_down(acc, off, 64);
        if (lane == 0)
            styles[b * CIN + ci] = acc * 0.04419417382415922f + ab[ci];
    }
}

// ---- weights: wsq fp32 + pre-flipped bf16 pack wb[cc][t][ci_hi][cout][ci_lo] ----
__global__ void prep_weights(const float* __restrict__ weight,
                             float* __restrict__ wsq,
                             __hip_bfloat16* __restrict__ wb) {
    int idx = blockIdx.x * 256 + threadIdx.x;   // 262144
    int co = idx & (COUT - 1);
    int ci = idx >> 9;
    const float* wp = weight + ((size_t)co * CIN + ci) * 9;
    int cc = ci >> 5, chi = (ci >> 3) & 3, clo = ci & 7;
    float s = 0.f;
#pragma unroll
    for (int t = 0; t < 9; ++t) {
        float v = wp[t];
        s += v * v;
        int tf = 8 - t;   // flipped tap
        wb[((((size_t)cc * 9 + tf) * 4 + chi) * COUT + co) * 8 + clo] = __float2bfloat16(v);
    }
    wsq[(size_t)co * CIN + ci] = s;
}

// ---------------- dcoef[b,co] = rsqrt( sum_ci wsq[co,ci]*styles^2 + 1e-8 ) ----------------
__global__ void dcoef2_kernel(const float* __restrict__ styles,
                              const float* __restrict__ wsq,
                              float* __restrict__ dcoef) {
    int b = blockIdx.x;          // 16
    int cog = blockIdx.y;        // 8
    int lane = threadIdx.x & 63, wv = threadIdx.x >> 6;
    __shared__ float s2[CIN];
    for (int e = threadIdx.x; e < CIN; e += 256) {
        float s = styles[b * CIN + e];
        s2[e] = s * s;
    }
    __syncthreads();
    for (int r = 0; r < 16; ++r) {
        int co = cog * 64 + wv * 16 + r;
        const float* qrow = wsq + (size_t)co * CIN;
        float acc = 0.f;
        for (int k = lane; k < CIN; k += 64) acc += qrow[k] * s2[k];
        for (int off = 32; off; off >>= 1) acc += __shfl_down(acc, off, 64);
        if (lane == 0) dcoef[b * COUT + co] = rsqrtf(acc + 1e-8f);
    }
}

// ------- fused upsample x2 (upfirdn [1,3,3,1]/8) * styles -> channels-last bf16 -------
// xs2[b][row(66)][col(66)][ci(512)]
__global__ void upmod2_kernel(const float* __restrict__ x,
                              const float* __restrict__ styles,
                              __hip_bfloat16* __restrict__ xs2) {
    __shared__ float xt[128 * 65];
    const int oh = blockIdx.x;        // 0..65
    const int ci0 = blockIdx.y * 128; // 4 groups
    const int b = blockIdx.z;
    int m0, m1; float a0, a1;
    if (oh & 1) { m0 = (oh - 3) >> 1; a0 = 0.125f; m1 = (oh - 1) >> 1; a1 = 0.375f; }
    else        { m0 = (oh >> 1) - 1; a0 = 0.375f; m1 = (oh >> 1);     a1 = 0.125f; }
    for (int e = threadIdx.x; e < 8192; e += 256) {
        int ci = e >> 6, sel = (e >> 5) & 1, iw = e & 31;
        int m = sel ? m1 : m0;
        float v = 0.f;
        if (m >= 0 && m < HIN)
            v = x[((size_t)(b * CIN + ci0 + ci) * HIN + m) * HIN + iw];
        xt[ci * 65 + sel * 32 + iw] = v;
    }
    __syncthreads();
    for (int e = threadIdx.x; e < 66 * 128; e += 256) {
        int ci = e & 127, ow = e >> 7;
        int n0i, n1i; float b0, b1;
        if (ow & 1) { n0i = (ow - 3) >> 1; b0 = 0.125f; n1i = (ow - 1) >> 1; b1 = 0.375f; }
        else        { n0i = (ow >> 1) - 1; b0 = 0.375f; n1i = (ow >> 1);     b1 = 0.125f; }
        bool c0 = (n0i >= 0) & (n0i < HIN);
        bool c1 = (n1i >= 0) & (n1i < HIN);
        float r0 = (c0 ? xt[ci * 65 + n0i] : 0.f) * b0 + (c1 ? xt[ci * 65 + n1i] : 0.f) * b1;
        float r1 = (c0 ? xt[ci * 65 + 32 + n0i] : 0.f) * b0 + (c1 ? xt[ci * 65 + 32 + n1i] : 0.f) * b1;
        float s = styles[b * CIN + ci0 + ci] * 4.0f;
        float val = (a0 * r0 + a1 * r1) * s;
        xs2[(((size_t)b * HUP + oh) * HUP + ow) * CIN + ci0 + ci] = __float2bfloat16(val);
    }
}

// ---------------- implicit-GEMM conv via MFMA bf16 16x16x32 ----------------
// block: 4 waves; tile M=256 px (4 image rows), N=64 cout; K-chunk = 32 ci.
// LDS A: [r(6)][ci_hi(4)][col(66)][ci_lo(8)] bf16 = 25344 B (padded to 25600)
// LDS B: [t(9)][ci_hi(4)][n(64)][ci_lo(8)]  bf16 = 36864 B
#define LDA_SZ 25600
#define LDB_SZ 36864

__global__ __launch_bounds__(256, 2) void conv_mfma(
        const __hip_bfloat16* __restrict__ xs2,
        const __hip_bfloat16* __restrict__ wb,
        const float* __restrict__ dcoef,
        const float* __restrict__ bias,
        const float* __restrict__ noise,
        const float* __restrict__ nstr,
        float* __restrict__ out)
{
    __shared__ __align__(16) char smem[LDA_SZ + LDB_SZ];
    const int tid = threadIdx.x;
    const int lane = tid & 63;
    const int wid = tid >> 6;
    const int li = lane & 15;
    const int q = lane >> 4;
    const int mt = blockIdx.x;        // 0..15 -> rows y0..y0+3
    const int n0 = blockIdx.y * 64;   // cout base
    const int b  = blockIdx.z;
    const int y0 = mt * 4;

    // ---- precompute staging descriptors ----
    long a_goff[7];   // element offsets into xs2 (without ci0)
    int  a_lds[7];
#pragma unroll
    for (int k = 0; k < 7; ++k) {
        int n = wid + k * 4;
        if (n < 25) {
            int s = n * 64 + lane;          // 16B slot id
            if (s > 1583) s = 1583;         // clamp tail into pad region
            int r = s / 264;
            int rem = s - r * 264;
            int chi = rem / 66;
            int col = rem - chi * 66;
            a_goff[k] = ((long)(b * HUP + y0 + r) * HUP + col) * CIN + chi * 8;
            a_lds[k] = n * 1024;
        } else { a_goff[k] = 0; a_lds[k] = -1; }
    }
    long b_goff[9];   // element offsets into wb (without cc term)
#pragma unroll
    for (int k = 0; k < 9; ++k) {
        int sl = wid + k * 4;               // 0..35: t = sl>>2, chi = sl&3
        b_goff[k] = ((long)sl * COUT + n0) * 8 + (long)lane * 8;
    }

    float4v acc[4][4];
#pragma unroll
    for (int i = 0; i < 4; ++i)
#pragma unroll
        for (int j = 0; j < 4; ++j) acc[i][j] = (float4v)0.f;

    const char* xg = (const char*)xs2;
    const char* wg = (const char*)wb;

    for (int cc = 0; cc < 16; ++cc) {
        // B: 36 x 1KB slices, 9 per wave
#pragma unroll
        for (int k = 0; k < 9; ++k) {
            int sl = wid + k * 4;
            long ge = (long)cc * 147456 + b_goff[k];
            __builtin_amdgcn_global_load_lds(
                (const __attribute__((address_space(1))) char*)(wg + ge * 2),
                (__attribute__((address_space(3))) char*)(smem + LDA_SZ + sl * 1024),
                16, 0, 0);
        }
        // A: 25 x 1KB slices (last partially duplicated into pad)
#pragma unroll
        for (int k = 0; k < 7; ++k) {
            if (a_lds[k] >= 0) {
                long ge = a_goff[k] + (long)cc * 32;
                __builtin_amdgcn_global_load_lds(
                    (const __attribute__((address_space(1))) char*)(xg + ge * 2),
                    (__attribute__((address_space(3))) char*)(smem + a_lds[k]),
                    16, 0, 0);
            }
        }
        __syncthreads();

#pragma unroll
        for (int t = 0; t < 9; ++t) {
            const int kh = t / 3, kw = t - kh * 3;
            short8 bf[4];
#pragma unroll
            for (int j = 0; j < 4; ++j)
                bf[j] = *(const short8*)(smem + LDA_SZ +
                        (((t * 4 + q) * 64) + j * 16 + li) * 16);
#pragma unroll
            for (int i = 0; i < 4; ++i) {
                short8 af = *(const short8*)(smem +
                        ((((wid + kh) * 4 + q) * 66) + (i * 16 + li + kw)) * 16);
#pragma unroll
                for (int j = 0; j < 4; ++j)
                    acc[i][j] = __builtin_amdgcn_mfma_f32_16x16x32_bf16(
                        af, bf[j], acc[i][j], 0, 0, 0);
            }
        }
        __syncthreads();
    }

    // ---- epilogue: *dcoef + noise + bias -> lrelu*gain ----
    const float ns = nstr[0];
    const int row = y0 + wid;
#pragma unroll
    for (int j = 0; j < 4; ++j) {
        int cout = n0 + j * 16 + li;
        float dc = dcoef[b * COUT + cout];
        float bs = bias[cout];
        float* op = out + ((size_t)(b * COUT + cout) * RES + row) * RES;
#pragma unroll
        for (int i = 0; i < 4; ++i) {
            int colb = i * 16 + q * 4;
            float4v nz = *(const float4v*)(noise + row * RES + colb);
            float4v a = acc[i][j];
            float4v r;
            r.x = a.x * dc + nz.x * ns + bs;
            r.y = a.y * dc + nz.y * ns + bs;
            r.z = a.z * dc + nz.z * ns + bs;
            r.w = a.w * dc + nz.w * ns + bs;
            r.x = (r.x > 0.f ? r.x : LRELU * r.x) * ACT_GAIN;
            r.y = (r.y > 0.f ? r.y : LRELU * r.y) * ACT_GAIN;
            r.z = (r.z > 0.f ? r.z : LRELU * r.z) * ACT_GAIN;
            r.w = (r.w > 0.f ? r.w : LRELU * r.w) * ACT_GAIN;
            *(float4v*)(op + colb) = r;
        }
    }
}

extern "C" void kernel_launch(void* const* d_in, const int* in_sizes, int n_in,
                              void* d_out, int out_size, void* d_ws, size_t ws_size,
                              hipStream_t stream) {
    (void)in_sizes; (void)n_in; (void)out_size; (void)ws_size;
    const float* x     = (const float*)d_in[0];
    const float* w     = (const float*)d_in[1];
    const float* aw    = (const float*)d_in[2];
    const float* ab    = (const float*)d_in[3];
    const float* wt    = (const float*)d_in[4];
    const float* bias  = (const float*)d_in[5];
    const float* noise = (const float*)d_in[6];
    const float* nstr  = (const float*)d_in[7];
    float* out = (float*)d_out;

    char* ws = (char*)d_ws;
    float* styles = (float*)ws;                                   // 32 KB
    float* dcoef  = (float*)(ws + 32768);                         // 32 KB
    float* wsq    = (float*)(ws + 65536);                         // 1 MB
    __hip_bfloat16* wb  = (__hip_bfloat16*)(ws + 65536 + 1048576);          // 4.72 MB
    __hip_bfloat16* xs2 = (__hip_bfloat16*)(ws + 65536 + 1048576 + 4718592); // 71.4 MB

    styles2_kernel<<<dim3(NB, 8), dim3(256), 0, stream>>>(w, aw, ab, styles);
    prep_weights<<<dim3(1024), dim3(256), 0, stream>>>(wt, wsq, wb);
    dcoef2_kernel<<<dim3(NB, 8), dim3(256), 0, stream>>>(styles, wsq, dcoef);
    upmod2_kernel<<<dim3(HUP, 4, NB), dim3(256), 0, stream>>>(x, styles, xs2);
    conv_mfma<<<dim3(16, 8, NB), dim3(256), 0, stream>>>(
        xs2, wb, dcoef, bias, noise, nstr, out);
}